// Round 15
// baseline (20.681 us; speedup 1.0000x reference)
//
#include <hip/hip_runtime.h>
#include <stdint.h>

#define KBOX 1024
#define EPSF 1e-4f
#define SLACK 3e-5f
#define ACT_TILES 1280     // row-pair triangular: 128*1 + 128*2 + 128*3 + 128*4
#define POSE_BLOCKS 4      // 4*256 = 1024 boxes -> hposed output

// ws layout (bytes):
//   0      : bm [K][16] u64    (128 KB) inside bitmask words (active words only)
//   131072 : tileCnt [K][4] u32 (16 KB)  only j*256<=k entries written/read
#define BM_OFF 0
#define TC_OFF 131072

// double-precision analytic inverse of the affine 3x4 (rows of A) -> 12 floats
__device__ inline void inv_affine(const float r[12], float* o) {
    double m00 = r[0], m01 = r[1], m02 = r[2];
    double m10 = r[4], m11 = r[5], m12 = r[6];
    double m20 = r[8], m21 = r[9], m22 = r[10];
    double c00 = m11 * m22 - m12 * m21;
    double c01 = m12 * m20 - m10 * m22;
    double c02 = m10 * m21 - m11 * m20;
    double det = m00 * c00 + m01 * c01 + m02 * c02;
    double id = 1.0 / det;
    double i00 = c00 * id, i01 = (m02 * m21 - m01 * m22) * id, i02 = (m01 * m12 - m02 * m11) * id;
    double i10 = c01 * id, i11 = (m00 * m22 - m02 * m20) * id, i12 = (m02 * m10 - m00 * m12) * id;
    double i20 = c02 * id, i21 = (m01 * m20 - m00 * m21) * id, i22 = (m00 * m11 - m01 * m10) * id;
    double tx = r[3], ty = r[7], tz = r[11];
    o[0] = (float)i00; o[1] = (float)i01; o[2] = (float)i02;
    o[3] = (float)(-(i00 * tx + i01 * ty + i02 * tz));
    o[4] = (float)i10; o[5] = (float)i11; o[6] = (float)i12;
    o[7] = (float)(-(i10 * tx + i11 * ty + i12 * tz));
    o[8] = (float)i20; o[9] = (float)i21; o[10] = (float)i22;
    o[11] = (float)(-(i20 * tx + i21 * ty + i22 * tz));
}

__global__ void k_main(const float* __restrict__ bbmin, const float* __restrict__ bbmax,
                       const float* __restrict__ A, const uint8_t* __restrict__ disB,
                       float* __restrict__ out_hposed,
                       uint64_t* __restrict__ bm, uint32_t* __restrict__ tileCnt) {
    int bid = blockIdx.x;
    int t = threadIdx.x;

    if (bid >= ACT_TILES) {  // pose blocks: write hposed (output 0)
        int k = (bid - ACT_TILES) * 256 + t;
        float r[12];
#pragma unroll
        for (int i = 0; i < 3; ++i) {
            float4 a4 = *(const float4*)(A + (size_t)k * 16 + i * 4);
            r[i * 4 + 0] = a4.x; r[i * 4 + 1] = a4.y; r[i * 4 + 2] = a4.z; r[i * 4 + 3] = a4.w;
        }
        float bmn[3], bmx[3];
#pragma unroll
        for (int i = 0; i < 3; ++i) { bmn[i] = bbmin[k * 3 + i]; bmx[i] = bbmax[k * 3 + i]; }
#pragma unroll
        for (int c = 0; c < 8; ++c) {
            float cx = ((c >> 2) & 1) ? bmx[0] : bmn[0];
            float cy = ((c >> 1) & 1) ? bmx[1] : bmn[1];
            float cz = (c & 1) ? bmx[2] : bmn[2];
#pragma unroll
            for (int i = 0; i < 3; ++i)
                out_hposed[(size_t)k * 24 + c * 3 + i] =
                    r[i * 4 + 0] * cx + r[i * 4 + 1] * cy + r[i * 4 + 2] * cz + r[i * 4 + 3];
        }
        return;
    }

    // row-pair triangular bid -> (group g -> rows 2g,2g+1 ; col tile j)
    int g, j;
    if (bid < 128)       { g = bid;                       j = 0; }
    else if (bid < 384)  { g = 128 + ((bid - 128) >> 1);  j = (bid - 128) & 1; }
    else if (bid < 768)  { g = 256 + (bid - 384) / 3;     j = (bid - 384) % 3; }
    else                 { g = 384 + ((bid - 768) >> 2);  j = (bid - 768) & 3; }
    int k1 = 2 * g;  // rows k1, k1+1
    int lane = t & 63, wave = t >> 6;
    int l = j * 256 + t;

    // dis layout detect, per-wave (no LDS/sync): int32 0/1 data has all high
    // bytes zero in the first 256 B; random bools don't
    uint32_t dwv = ((const uint32_t*)disB)[lane];
    const bool isBool = __ballot((dwv & 0xFFFFFF00u) != 0 ? 1 : 0) != 0ull;

    // col data: loaded ONCE, serves both rows
    float rl[12];
#pragma unroll
    for (int i = 0; i < 3; ++i) {
        float4 a4 = *(const float4*)(A + (size_t)l * 16 + i * 4);
        rl[i * 4 + 0] = a4.x; rl[i * 4 + 1] = a4.y; rl[i * 4 + 2] = a4.z; rl[i * 4 + 3] = a4.w;
    }
    float bmnl[3], bmxl[3];
#pragma unroll
    for (int i = 0; i < 3; ++i) { bmnl[i] = bbmin[l * 3 + i]; bmxl[i] = bbmax[l * 3 + i]; }
    float wcl[3], whl[3];
    {
        float cx = 0.5f * (bmnl[0] + bmxl[0]), hx = 0.5f * (bmxl[0] - bmnl[0]);
        float cy = 0.5f * (bmnl[1] + bmxl[1]), hy = 0.5f * (bmxl[1] - bmnl[1]);
        float cz = 0.5f * (bmnl[2] + bmxl[2]), hz = 0.5f * (bmxl[2] - bmnl[2]);
#pragma unroll
        for (int i = 0; i < 3; ++i) {
            wcl[i] = rl[i * 4 + 0] * cx + rl[i * 4 + 1] * cy + rl[i * 4 + 2] * cz + rl[i * 4 + 3];
            whl[i] = fabsf(rl[i * 4 + 0]) * hx + fabsf(rl[i * 4 + 1]) * hy + fabsf(rl[i * 4 + 2]) * hz;
        }
    }

    __shared__ uint32_t wcnt[2][4];

    for (int rr = 0; rr < 2; ++rr) {
        int k = k1 + rr;
        if (j * 256 > k) continue;  // block-uniform; only possible for rr=0

        // row data: broadcast loads (all lanes same address -> L1 line hit)
        float rk[12];
#pragma unroll
        for (int i = 0; i < 3; ++i) {
            float4 a4 = *(const float4*)(A + (size_t)k * 16 + i * 4);
            rk[i * 4 + 0] = a4.x; rk[i * 4 + 1] = a4.y; rk[i * 4 + 2] = a4.z; rk[i * 4 + 3] = a4.w;
        }
        float bmnk[3], bmxk[3];
#pragma unroll
        for (int i = 0; i < 3; ++i) { bmnk[i] = bbmin[k * 3 + i]; bmxk[i] = bbmax[k * 3 + i]; }
        float wmnk[3], wmxk[3];
        {
            float cx = 0.5f * (bmnk[0] + bmxk[0]), hx = 0.5f * (bmxk[0] - bmnk[0]);
            float cy = 0.5f * (bmnk[1] + bmxk[1]), hy = 0.5f * (bmxk[1] - bmnk[1]);
            float cz = 0.5f * (bmnk[2] + bmxk[2]), hz = 0.5f * (bmxk[2] - bmnk[2]);
#pragma unroll
            for (int i = 0; i < 3; ++i) {
                float c = rk[i * 4 + 0] * cx + rk[i * 4 + 1] * cy + rk[i * 4 + 2] * cz + rk[i * 4 + 3];
                float h = fabsf(rk[i * 4 + 0]) * hx + fabsf(rk[i * 4 + 1]) * hy +
                          fabsf(rk[i * 4 + 2]) * hz;
                wmnk[i] = c - h - SLACK;
                wmxk[i] = c + h + SLACK;
            }
        }

        bool cand = false;
        if (l <= k) {
            cand = (wcl[0] - whl[0] <= wmxk[0]) & (wmnk[0] <= wcl[0] + whl[0]) &
                   (wcl[1] - whl[1] <= wmxk[1]) & (wmnk[1] <= wcl[1] + whl[1]) &
                   (wcl[2] - whl[2] <= wmxk[2]) & (wmnk[2] <= wcl[2] + whl[2]);
        }
        bool bit = false, dA = false, dB = false;
        if (cand) {  // dis bits only for AABB candidates (~1% of pairs)
            if (isBool) {
                dA = disB[(size_t)k * KBOX + l] != 0;
                dB = disB[(size_t)l * KBOX + k] != 0;
            } else {
                const int* disI = (const int*)disB;
                dA = disI[(size_t)k * KBOX + l] != 0;
                dB = disI[(size_t)l * KBOX + k] != 0;
            }
        }
        if (cand && (dA | dB)) {  // rare heavy path: per-lane, formulas identical
            if (dA) {  // corners of l into frame k
                float bk[12];
                inv_affine(rk, bk);
                bool rawA = false;
#pragma unroll
                for (int c = 0; c < 8; ++c) {
                    float cx = ((c >> 2) & 1) ? bmxl[0] : bmnl[0];
                    float cy = ((c >> 1) & 1) ? bmxl[1] : bmnl[1];
                    float cz = (c & 1) ? bmxl[2] : bmnl[2];
                    float px = rl[0] * cx + rl[1] * cy + rl[2] * cz + rl[3];
                    float py = rl[4] * cx + rl[5] * cy + rl[6] * cz + rl[7];
                    float pz = rl[8] * cx + rl[9] * cy + rl[10] * cz + rl[11];
                    float x = bk[0] * px + bk[1] * py + bk[2] * pz + bk[3];
                    float y = bk[4] * px + bk[5] * py + bk[6] * pz + bk[7];
                    float z = bk[8] * px + bk[9] * py + bk[10] * pz + bk[11];
                    rawA = rawA || (x > bmnk[0] + EPSF && x < bmxk[0] - EPSF &&
                                    y > bmnk[1] + EPSF && y < bmxk[1] - EPSF &&
                                    z > bmnk[2] + EPSF && z < bmxk[2] - EPSF);
                }
                bit = rawA;
            }
            if (dB && !bit) {  // corners of k into frame l
                float bl[12];
                inv_affine(rl, bl);
                bool rawB = false;
#pragma unroll
                for (int c = 0; c < 8; ++c) {
                    float cx = ((c >> 2) & 1) ? bmxk[0] : bmnk[0];
                    float cy = ((c >> 1) & 1) ? bmxk[1] : bmnk[1];
                    float cz = (c & 1) ? bmxk[2] : bmnk[2];
                    float px = rk[0] * cx + rk[1] * cy + rk[2] * cz + rk[3];
                    float py = rk[4] * cx + rk[5] * cy + rk[6] * cz + rk[7];
                    float pz = rk[8] * cx + rk[9] * cy + rk[10] * cz + rk[11];
                    float x = bl[0] * px + bl[1] * py + bl[2] * pz + bl[3];
                    float y = bl[4] * px + bl[5] * py + bl[6] * pz + bl[7];
                    float z = bl[8] * px + bl[9] * py + bl[10] * pz + bl[11];
                    rawB = rawB || (x > bmnl[0] + EPSF && x < bmxl[0] - EPSF &&
                                    y > bmnl[1] + EPSF && y < bmxl[1] - EPSF &&
                                    z > bmnl[2] + EPSF && z < bmxl[2] - EPSF);
                }
                bit = rawB;
            }
        }
        uint64_t word = __ballot(bit ? 1 : 0);
        if (lane == 0) {
            bm[(size_t)k * 16 + j * 4 + wave] = word;
            wcnt[rr][wave] = (uint32_t)__popcll(word);
        }
    }
    __syncthreads();
    if (t == 0) {
        if (j * 256 <= k1)
            tileCnt[(size_t)k1 * 4 + j] = wcnt[0][0] + wcnt[0][1] + wcnt[0][2] + wcnt[0][3];
        tileCnt[(size_t)(k1 + 1) * 4 + j] = wcnt[1][0] + wcnt[1][1] + wcnt[1][2] + wcnt[1][3];
    }
}

// 256 blocks x 256 threads: block b owns rows 4b..4b+3 (one per wave) and a
// 1/256 slice of the complement -1 fill.
__global__ void k_compact(const uint64_t* __restrict__ bm,
                          const uint32_t* __restrict__ tileCnt, float* __restrict__ out) {
    int b = blockIdx.x;
    int t = threadIdx.x;
    int wave = t >> 6, lane = t & 63;
    int k0 = 4 * b;
    __shared__ uint32_t baseW[4], totW[4], rowc[4];

    // per-thread: 4 strided rows; mask tile components by validity (j*256<=row)
    uint32_t sm = 0, st = 0;
#pragma unroll
    for (int rr = 0; rr < 4; ++rr) {
        int row = t + rr * 256;
        uint4 c4 = *(const uint4*)(tileCnt + (size_t)row * 4);
        uint32_t v = c4.x + ((row >= 256) ? c4.y : 0u) + ((row >= 512) ? c4.z : 0u) +
                     ((row >= 768) ? c4.w : 0u);
        sm += (row < k0) ? v : 0u;
        st += v;
    }
#pragma unroll
    for (int off = 32; off > 0; off >>= 1) { sm += __shfl_xor(sm, off); st += __shfl_xor(st, off); }
    if (lane == 0) { baseW[wave] = sm; totW[wave] = st; }
    if (t < 4) {  // in-block row counts
        int row = k0 + t;
        uint4 c4 = *(const uint4*)(tileCnt + (size_t)row * 4);
        rowc[t] = c4.x + ((row >= 256) ? c4.y : 0u) + ((row >= 512) ? c4.z : 0u) +
                  ((row >= 768) ? c4.w : 0u);
    }
    __syncthreads();
    uint32_t base = baseW[0] + baseW[1] + baseW[2] + baseW[3];
    uint32_t total = totW[0] + totW[1] + totW[2] + totW[3];

    // complement fill: positions [total, K*K) in float2 units get (-1,-1);
    // pair writes below cover [0, total) exactly -> disjoint, race-free.
    float2* o2 = (float2*)out;
    for (uint32_t i = total + (uint32_t)b * 256 + t; i < (uint32_t)(KBOX * KBOX); i += 256 * 256)
        o2[i] = make_float2(-1.f, -1.f);

    // wave w compacts row k0+w
    uint32_t startw = base;
#pragma unroll
    for (int r = 0; r < 4; ++r)
        if (r < wave) startw += rowc[r];
    int k = k0 + wave;
    uint64_t w = (lane < 16 && lane * 64 <= k) ? bm[(size_t)k * 16 + lane] : 0ull;
    int c = (int)__popcll(w);
    int p = c;
#pragma unroll
    for (int off = 1; off < 64; off <<= 1) {
        int u = __shfl_up(p, off);
        if (lane >= off) p += u;
    }
    int ofs = (int)startw + (p - c);
    float fk = (float)k;
    while (w) {
        int bpos = __builtin_ctzll(w);
        int col = lane * 64 + bpos;
        out[2 * (size_t)ofs + 0] = (float)col;  // min = col (tril => col <= row)
        out[2 * (size_t)ofs + 1] = fk;          // max = row
        ++ofs;
        w &= w - 1;
    }
}

extern "C" void kernel_launch(void* const* d_in, const int* in_sizes, int n_in,
                              void* d_out, int out_size, void* d_ws, size_t ws_size,
                              hipStream_t stream) {
    const float* bbmin = (const float*)d_in[0];
    const float* bbmax = (const float*)d_in[1];
    const float* A = (const float*)d_in[2];
    const uint8_t* dis = (const uint8_t*)d_in[3];
    float* out = (float*)d_out;

    char* ws = (char*)d_ws;
    uint64_t* bm = (uint64_t*)(ws + BM_OFF);
    uint32_t* tileCnt = (uint32_t*)(ws + TC_OFF);

    k_main<<<ACT_TILES + POSE_BLOCKS, 256, 0, stream>>>(
        bbmin, bbmax, A, dis, out, bm, tileCnt);
    k_compact<<<256, 256, 0, stream>>>(bm, tileCnt, out + KBOX * 24);
}

// Round 16
// 19.785 us; speedup vs baseline: 1.0453x; 1.0453x over previous
//
#include <hip/hip_runtime.h>
#include <stdint.h>

#define KBOX 1024
#define EPSF 1e-4f
#define SLACK 3e-5f
#define ACT_TILES 2560     // triangular: 256*1 + 256*2 + 256*3 + 256*4
#define POSE_BLOCKS 4      // 4*256 = 1024 boxes -> hposed output

// ws layout (bytes):
//   0      : bm [K][16] u64     (128 KB) inside bitmask words (active words only)
//   131072 : tc16 [K][16] u32   (64 KB)  per-wave counts (active words only)
#define BM_OFF 0
#define TC_OFF 131072

// double-precision analytic inverse of the affine 3x4 (rows of A) -> 12 floats
__device__ inline void inv_affine(const float r[12], float* o) {
    double m00 = r[0], m01 = r[1], m02 = r[2];
    double m10 = r[4], m11 = r[5], m12 = r[6];
    double m20 = r[8], m21 = r[9], m22 = r[10];
    double c00 = m11 * m22 - m12 * m21;
    double c01 = m12 * m20 - m10 * m22;
    double c02 = m10 * m21 - m11 * m20;
    double det = m00 * c00 + m01 * c01 + m02 * c02;
    double id = 1.0 / det;
    double i00 = c00 * id, i01 = (m02 * m21 - m01 * m22) * id, i02 = (m01 * m12 - m02 * m11) * id;
    double i10 = c01 * id, i11 = (m00 * m22 - m02 * m20) * id, i12 = (m02 * m10 - m00 * m12) * id;
    double i20 = c02 * id, i21 = (m01 * m20 - m00 * m21) * id, i22 = (m00 * m11 - m01 * m10) * id;
    double tx = r[3], ty = r[7], tz = r[11];
    o[0] = (float)i00; o[1] = (float)i01; o[2] = (float)i02;
    o[3] = (float)(-(i00 * tx + i01 * ty + i02 * tz));
    o[4] = (float)i10; o[5] = (float)i11; o[6] = (float)i12;
    o[7] = (float)(-(i10 * tx + i11 * ty + i12 * tz));
    o[8] = (float)i20; o[9] = (float)i21; o[10] = (float)i22;
    o[11] = (float)(-(i20 * tx + i21 * ty + i22 * tz));
}

__global__ void k_main(const float* __restrict__ bbmin, const float* __restrict__ bbmax,
                       const float* __restrict__ A, const uint8_t* __restrict__ disB,
                       float* __restrict__ out_hposed,
                       uint64_t* __restrict__ bm, uint32_t* __restrict__ tc16) {
    int bid = blockIdx.x;
    int t = threadIdx.x;

    if (bid >= ACT_TILES) {  // pose blocks: write hposed (output 0)
        int k = (bid - ACT_TILES) * 256 + t;
        float r[12];
#pragma unroll
        for (int i = 0; i < 3; ++i) {
            float4 a4 = *(const float4*)(A + (size_t)k * 16 + i * 4);
            r[i * 4 + 0] = a4.x; r[i * 4 + 1] = a4.y; r[i * 4 + 2] = a4.z; r[i * 4 + 3] = a4.w;
        }
        float bmn[3], bmx[3];
#pragma unroll
        for (int i = 0; i < 3; ++i) { bmn[i] = bbmin[k * 3 + i]; bmx[i] = bbmax[k * 3 + i]; }
#pragma unroll
        for (int c = 0; c < 8; ++c) {
            float cx = ((c >> 2) & 1) ? bmx[0] : bmn[0];
            float cy = ((c >> 1) & 1) ? bmx[1] : bmn[1];
            float cz = (c & 1) ? bmx[2] : bmn[2];
#pragma unroll
            for (int i = 0; i < 3; ++i)
                out_hposed[(size_t)k * 24 + c * 3 + i] =
                    r[i * 4 + 0] * cx + r[i * 4 + 1] * cy + r[i * 4 + 2] * cz + r[i * 4 + 3];
        }
        return;
    }

    // triangular bid -> (row k, col tile j); only below-diagonal tiles exist
    int k, j;
    if (bid < 256)       { k = bid;                      j = 0; }
    else if (bid < 768)  { k = 256 + ((bid - 256) >> 1); j = (bid - 256) & 1; }
    else if (bid < 1536) { k = 512 + (bid - 768) / 3;    j = (bid - 768) % 3; }
    else                 { k = 768 + ((bid - 1536) >> 2);j = (bid - 1536) & 3; }
    int lane = t & 63, wave = t >> 6;
    int l = j * 256 + t;

    // dis layout detect, per-wave (no LDS/sync): int32 0/1 data has all high
    // bytes zero in the first 256 B; random bools don't
    uint32_t dwv = ((const uint32_t*)disB)[lane];
    const bool isBool = __ballot((dwv & 0xFFFFFF00u) != 0 ? 1 : 0) != 0ull;

    // row data: broadcast loads (all lanes same address -> L1 line hit)
    float rk[12];
#pragma unroll
    for (int i = 0; i < 3; ++i) {
        float4 a4 = *(const float4*)(A + (size_t)k * 16 + i * 4);
        rk[i * 4 + 0] = a4.x; rk[i * 4 + 1] = a4.y; rk[i * 4 + 2] = a4.z; rk[i * 4 + 3] = a4.w;
    }
    float bmnk[3], bmxk[3];
#pragma unroll
    for (int i = 0; i < 3; ++i) { bmnk[i] = bbmin[k * 3 + i]; bmxk[i] = bbmax[k * 3 + i]; }
    float wmnk[3], wmxk[3];
    {
        float cx = 0.5f * (bmnk[0] + bmxk[0]), hx = 0.5f * (bmxk[0] - bmnk[0]);
        float cy = 0.5f * (bmnk[1] + bmxk[1]), hy = 0.5f * (bmxk[1] - bmnk[1]);
        float cz = 0.5f * (bmnk[2] + bmxk[2]), hz = 0.5f * (bmxk[2] - bmnk[2]);
#pragma unroll
        for (int i = 0; i < 3; ++i) {
            float c = rk[i * 4 + 0] * cx + rk[i * 4 + 1] * cy + rk[i * 4 + 2] * cz + rk[i * 4 + 3];
            float h = fabsf(rk[i * 4 + 0]) * hx + fabsf(rk[i * 4 + 1]) * hy + fabsf(rk[i * 4 + 2]) * hz;
            wmnk[i] = c - h - SLACK;
            wmxk[i] = c + h + SLACK;
        }
    }

    // col data
    float rl[12];
#pragma unroll
    for (int i = 0; i < 3; ++i) {
        float4 a4 = *(const float4*)(A + (size_t)l * 16 + i * 4);
        rl[i * 4 + 0] = a4.x; rl[i * 4 + 1] = a4.y; rl[i * 4 + 2] = a4.z; rl[i * 4 + 3] = a4.w;
    }
    float bmnl[3], bmxl[3];
#pragma unroll
    for (int i = 0; i < 3; ++i) { bmnl[i] = bbmin[l * 3 + i]; bmxl[i] = bbmax[l * 3 + i]; }
    float wcl[3], whl[3];
    {
        float cx = 0.5f * (bmnl[0] + bmxl[0]), hx = 0.5f * (bmxl[0] - bmnl[0]);
        float cy = 0.5f * (bmnl[1] + bmxl[1]), hy = 0.5f * (bmxl[1] - bmnl[1]);
        float cz = 0.5f * (bmnl[2] + bmxl[2]), hz = 0.5f * (bmxl[2] - bmnl[2]);
#pragma unroll
        for (int i = 0; i < 3; ++i) {
            wcl[i] = rl[i * 4 + 0] * cx + rl[i * 4 + 1] * cy + rl[i * 4 + 2] * cz + rl[i * 4 + 3];
            whl[i] = fabsf(rl[i * 4 + 0]) * hx + fabsf(rl[i * 4 + 1]) * hy + fabsf(rl[i * 4 + 2]) * hz;
        }
    }

    bool cand = false;
    if (l <= k) {
        cand = (wcl[0] - whl[0] <= wmxk[0]) & (wmnk[0] <= wcl[0] + whl[0]) &
               (wcl[1] - whl[1] <= wmxk[1]) & (wmnk[1] <= wcl[1] + whl[1]) &
               (wcl[2] - whl[2] <= wmxk[2]) & (wmnk[2] <= wcl[2] + whl[2]);
    }
    bool bit = false, dA = false, dB = false;
    if (cand) {  // dis bits only for AABB candidates (~1% of pairs)
        if (isBool) {
            dA = disB[(size_t)k * KBOX + l] != 0;
            dB = disB[(size_t)l * KBOX + k] != 0;
        } else {
            const int* disI = (const int*)disB;
            dA = disI[(size_t)k * KBOX + l] != 0;
            dB = disI[(size_t)l * KBOX + k] != 0;
        }
    }
    if (cand && (dA | dB)) {  // rare heavy path: per-lane, formulas identical
        if (dA) {  // corners of l into frame k
            float bk[12];
            inv_affine(rk, bk);
            bool rawA = false;
#pragma unroll
            for (int c = 0; c < 8; ++c) {
                float cx = ((c >> 2) & 1) ? bmxl[0] : bmnl[0];
                float cy = ((c >> 1) & 1) ? bmxl[1] : bmnl[1];
                float cz = (c & 1) ? bmxl[2] : bmnl[2];
                float px = rl[0] * cx + rl[1] * cy + rl[2] * cz + rl[3];
                float py = rl[4] * cx + rl[5] * cy + rl[6] * cz + rl[7];
                float pz = rl[8] * cx + rl[9] * cy + rl[10] * cz + rl[11];
                float x = bk[0] * px + bk[1] * py + bk[2] * pz + bk[3];
                float y = bk[4] * px + bk[5] * py + bk[6] * pz + bk[7];
                float z = bk[8] * px + bk[9] * py + bk[10] * pz + bk[11];
                rawA = rawA || (x > bmnk[0] + EPSF && x < bmxk[0] - EPSF &&
                                y > bmnk[1] + EPSF && y < bmxk[1] - EPSF &&
                                z > bmnk[2] + EPSF && z < bmxk[2] - EPSF);
            }
            bit = rawA;
        }
        if (dB && !bit) {  // corners of k into frame l
            float bl[12];
            inv_affine(rl, bl);
            bool rawB = false;
#pragma unroll
            for (int c = 0; c < 8; ++c) {
                float cx = ((c >> 2) & 1) ? bmxk[0] : bmnk[0];
                float cy = ((c >> 1) & 1) ? bmxk[1] : bmnk[1];
                float cz = (c & 1) ? bmxk[2] : bmnk[2];
                float px = rk[0] * cx + rk[1] * cy + rk[2] * cz + rk[3];
                float py = rk[4] * cx + rk[5] * cy + rk[6] * cz + rk[7];
                float pz = rk[8] * cx + rk[9] * cy + rk[10] * cz + rk[11];
                float x = bl[0] * px + bl[1] * py + bl[2] * pz + bl[3];
                float y = bl[4] * px + bl[5] * py + bl[6] * pz + bl[7];
                float z = bl[8] * px + bl[9] * py + bl[10] * pz + bl[11];
                rawB = rawB || (x > bmnl[0] + EPSF && x < bmxl[0] - EPSF &&
                                y > bmnl[1] + EPSF && y < bmxl[1] - EPSF &&
                                z > bmnl[2] + EPSF && z < bmxl[2] - EPSF);
            }
            bit = rawB;
        }
    }
    uint64_t word = __ballot(bit ? 1 : 0);
    if (lane == 0) {  // barrier-free tail: each wave publishes word + count
        int w = j * 4 + wave;
        bm[(size_t)k * 16 + w] = word;
        tc16[(size_t)k * 16 + w] = (uint32_t)__popcll(word);
    }
}

// masked row count: component w counted iff w*64 <= row (words beyond are
// provably all-zero ballots or unwritten)
__device__ inline uint32_t row_count(const uint32_t* __restrict__ tc16, int row) {
    const uint4* tc = (const uint4*)(tc16 + (size_t)row * 16);
    uint4 a0 = tc[0], a1 = tc[1], a2 = tc[2], a3 = tc[3];
    int q = row >> 6;
    uint32_t v = a0.x;
    v += (q >= 1) ? a0.y : 0u;  v += (q >= 2) ? a0.z : 0u;  v += (q >= 3) ? a0.w : 0u;
    v += (q >= 4) ? a1.x : 0u;  v += (q >= 5) ? a1.y : 0u;  v += (q >= 6) ? a1.z : 0u;
    v += (q >= 7) ? a1.w : 0u;  v += (q >= 8) ? a2.x : 0u;  v += (q >= 9) ? a2.y : 0u;
    v += (q >= 10) ? a2.z : 0u; v += (q >= 11) ? a2.w : 0u; v += (q >= 12) ? a3.x : 0u;
    v += (q >= 13) ? a3.y : 0u; v += (q >= 14) ? a3.z : 0u; v += (q >= 15) ? a3.w : 0u;
    return v;
}

// 256 blocks x 256 threads: block b owns rows 4b..4b+3 (one per wave) and a
// 1/256 slice of the complement -1 fill.
__global__ void k_compact(const uint64_t* __restrict__ bm,
                          const uint32_t* __restrict__ tc16, float* __restrict__ out) {
    int b = blockIdx.x;
    int t = threadIdx.x;
    int wave = t >> 6, lane = t & 63;
    int k0 = 4 * b;
    __shared__ uint32_t baseW[4], totW[4], rowc[4];

    uint32_t sm = 0, st = 0;
#pragma unroll
    for (int rr = 0; rr < 4; ++rr) {
        int row = t + rr * 256;
        uint32_t v = row_count(tc16, row);
        sm += (row < k0) ? v : 0u;
        st += v;
    }
#pragma unroll
    for (int off = 32; off > 0; off >>= 1) { sm += __shfl_xor(sm, off); st += __shfl_xor(st, off); }
    if (lane == 0) { baseW[wave] = sm; totW[wave] = st; }
    if (t < 4) rowc[t] = row_count(tc16, k0 + t);
    __syncthreads();
    uint32_t base = baseW[0] + baseW[1] + baseW[2] + baseW[3];
    uint32_t total = totW[0] + totW[1] + totW[2] + totW[3];

    // complement fill: positions [total, K*K) in float2 units get (-1,-1);
    // pair writes below cover [0, total) exactly -> disjoint, race-free.
    float2* o2 = (float2*)out;
    for (uint32_t i = total + (uint32_t)b * 256 + t; i < (uint32_t)(KBOX * KBOX); i += 256 * 256)
        o2[i] = make_float2(-1.f, -1.f);

    // wave w compacts row k0+w
    uint32_t startw = base;
#pragma unroll
    for (int r = 0; r < 4; ++r)
        if (r < wave) startw += rowc[r];
    int k = k0 + wave;
    uint64_t w = (lane < 16 && lane * 64 <= k) ? bm[(size_t)k * 16 + lane] : 0ull;
    int c = (int)__popcll(w);
    int p = c;
#pragma unroll
    for (int off = 1; off < 64; off <<= 1) {
        int u = __shfl_up(p, off);
        if (lane >= off) p += u;
    }
    int ofs = (int)startw + (p - c);
    float fk = (float)k;
    while (w) {
        int bpos = __builtin_ctzll(w);
        int col = lane * 64 + bpos;
        out[2 * (size_t)ofs + 0] = (float)col;  // min = col (tril => col <= row)
        out[2 * (size_t)ofs + 1] = fk;          // max = row
        ++ofs;
        w &= w - 1;
    }
}

extern "C" void kernel_launch(void* const* d_in, const int* in_sizes, int n_in,
                              void* d_out, int out_size, void* d_ws, size_t ws_size,
                              hipStream_t stream) {
    const float* bbmin = (const float*)d_in[0];
    const float* bbmax = (const float*)d_in[1];
    const float* A = (const float*)d_in[2];
    const uint8_t* dis = (const uint8_t*)d_in[3];
    float* out = (float*)d_out;

    char* ws = (char*)d_ws;
    uint64_t* bm = (uint64_t*)(ws + BM_OFF);
    uint32_t* tc16 = (uint32_t*)(ws + TC_OFF);

    k_main<<<ACT_TILES + POSE_BLOCKS, 256, 0, stream>>>(
        bbmin, bbmax, A, dis, out, bm, tc16);
    k_compact<<<256, 256, 0, stream>>>(bm, tc16, out + KBOX * 24);
}

// Round 17
// 19.457 us; speedup vs baseline: 1.0629x; 1.0169x over previous
//
#include <hip/hip_runtime.h>
#include <stdint.h>

#define KBOX 1024
#define EPSF 1e-4f
#define SLACK 3e-5f
#define ACT_TILES 2560     // triangular: 256*1 + 256*2 + 256*3 + 256*4

// ws layout (bytes):
//   0      : bm [K][16] u64    (128 KB) inside bitmask words (active words only)
//   131072 : tileCnt [K][4] u32 (16 KB)  only j*256<=k entries written/read
#define BM_OFF 0
#define TC_OFF 131072

// double-precision analytic inverse of the affine 3x4 (rows of A) -> 12 floats
__device__ inline void inv_affine(const float r[12], float* o) {
    double m00 = r[0], m01 = r[1], m02 = r[2];
    double m10 = r[4], m11 = r[5], m12 = r[6];
    double m20 = r[8], m21 = r[9], m22 = r[10];
    double c00 = m11 * m22 - m12 * m21;
    double c01 = m12 * m20 - m10 * m22;
    double c02 = m10 * m21 - m11 * m20;
    double det = m00 * c00 + m01 * c01 + m02 * c02;
    double id = 1.0 / det;
    double i00 = c00 * id, i01 = (m02 * m21 - m01 * m22) * id, i02 = (m01 * m12 - m02 * m11) * id;
    double i10 = c01 * id, i11 = (m00 * m22 - m02 * m20) * id, i12 = (m02 * m10 - m00 * m12) * id;
    double i20 = c02 * id, i21 = (m01 * m20 - m00 * m21) * id, i22 = (m00 * m11 - m01 * m10) * id;
    double tx = r[3], ty = r[7], tz = r[11];
    o[0] = (float)i00; o[1] = (float)i01; o[2] = (float)i02;
    o[3] = (float)(-(i00 * tx + i01 * ty + i02 * tz));
    o[4] = (float)i10; o[5] = (float)i11; o[6] = (float)i12;
    o[7] = (float)(-(i10 * tx + i11 * ty + i12 * tz));
    o[8] = (float)i20; o[9] = (float)i21; o[10] = (float)i22;
    o[11] = (float)(-(i20 * tx + i21 * ty + i22 * tz));
}

__global__ void k_main(const float* __restrict__ bbmin, const float* __restrict__ bbmax,
                       const float* __restrict__ A, const uint8_t* __restrict__ disB,
                       uint64_t* __restrict__ bm, uint32_t* __restrict__ tileCnt) {
    int bid = blockIdx.x;
    int t = threadIdx.x;

    // triangular bid -> (row k, col tile j); only below-diagonal tiles exist
    int k, j;
    if (bid < 256)       { k = bid;                      j = 0; }
    else if (bid < 768)  { k = 256 + ((bid - 256) >> 1); j = (bid - 256) & 1; }
    else if (bid < 1536) { k = 512 + (bid - 768) / 3;    j = (bid - 768) % 3; }
    else                 { k = 768 + ((bid - 1536) >> 2);j = (bid - 1536) & 3; }
    int lane = t & 63, wave = t >> 6;
    int l = j * 256 + t;

    // dis layout detect, per-wave (no LDS/sync): int32 0/1 data has all high
    // bytes zero in the first 256 B; random bools don't
    uint32_t dwv = ((const uint32_t*)disB)[lane];
    const bool isBool = __ballot((dwv & 0xFFFFFF00u) != 0 ? 1 : 0) != 0ull;

    // row data: broadcast loads (all lanes same address -> L1 line hit)
    float rk[12];
#pragma unroll
    for (int i = 0; i < 3; ++i) {
        float4 a4 = *(const float4*)(A + (size_t)k * 16 + i * 4);
        rk[i * 4 + 0] = a4.x; rk[i * 4 + 1] = a4.y; rk[i * 4 + 2] = a4.z; rk[i * 4 + 3] = a4.w;
    }
    float bmnk[3], bmxk[3];
#pragma unroll
    for (int i = 0; i < 3; ++i) { bmnk[i] = bbmin[k * 3 + i]; bmxk[i] = bbmax[k * 3 + i]; }
    float wmnk[3], wmxk[3];
    {
        float cx = 0.5f * (bmnk[0] + bmxk[0]), hx = 0.5f * (bmxk[0] - bmnk[0]);
        float cy = 0.5f * (bmnk[1] + bmxk[1]), hy = 0.5f * (bmxk[1] - bmnk[1]);
        float cz = 0.5f * (bmnk[2] + bmxk[2]), hz = 0.5f * (bmxk[2] - bmnk[2]);
#pragma unroll
        for (int i = 0; i < 3; ++i) {
            float c = rk[i * 4 + 0] * cx + rk[i * 4 + 1] * cy + rk[i * 4 + 2] * cz + rk[i * 4 + 3];
            float h = fabsf(rk[i * 4 + 0]) * hx + fabsf(rk[i * 4 + 1]) * hy + fabsf(rk[i * 4 + 2]) * hz;
            wmnk[i] = c - h - SLACK;
            wmxk[i] = c + h + SLACK;
        }
    }

    // col data
    float rl[12];
#pragma unroll
    for (int i = 0; i < 3; ++i) {
        float4 a4 = *(const float4*)(A + (size_t)l * 16 + i * 4);
        rl[i * 4 + 0] = a4.x; rl[i * 4 + 1] = a4.y; rl[i * 4 + 2] = a4.z; rl[i * 4 + 3] = a4.w;
    }
    float bmnl[3], bmxl[3];
#pragma unroll
    for (int i = 0; i < 3; ++i) { bmnl[i] = bbmin[l * 3 + i]; bmxl[i] = bbmax[l * 3 + i]; }
    float wcl[3], whl[3];
    {
        float cx = 0.5f * (bmnl[0] + bmxl[0]), hx = 0.5f * (bmxl[0] - bmnl[0]);
        float cy = 0.5f * (bmnl[1] + bmxl[1]), hy = 0.5f * (bmxl[1] - bmnl[1]);
        float cz = 0.5f * (bmnl[2] + bmxl[2]), hz = 0.5f * (bmxl[2] - bmnl[2]);
#pragma unroll
        for (int i = 0; i < 3; ++i) {
            wcl[i] = rl[i * 4 + 0] * cx + rl[i * 4 + 1] * cy + rl[i * 4 + 2] * cz + rl[i * 4 + 3];
            whl[i] = fabsf(rl[i * 4 + 0]) * hx + fabsf(rl[i * 4 + 1]) * hy + fabsf(rl[i * 4 + 2]) * hz;
        }
    }

    bool cand = false;
    if (l <= k) {
        cand = (wcl[0] - whl[0] <= wmxk[0]) & (wmnk[0] <= wcl[0] + whl[0]) &
               (wcl[1] - whl[1] <= wmxk[1]) & (wmnk[1] <= wcl[1] + whl[1]) &
               (wcl[2] - whl[2] <= wmxk[2]) & (wmnk[2] <= wcl[2] + whl[2]);
    }
    bool bit = false, dA = false, dB = false;
    if (cand) {  // dis bits only for AABB candidates (~1% of pairs)
        if (isBool) {
            dA = disB[(size_t)k * KBOX + l] != 0;
            dB = disB[(size_t)l * KBOX + k] != 0;
        } else {
            const int* disI = (const int*)disB;
            dA = disI[(size_t)k * KBOX + l] != 0;
            dB = disI[(size_t)l * KBOX + k] != 0;
        }
    }
    if (cand && (dA | dB)) {  // rare heavy path: per-lane, formulas identical
        if (dA) {  // corners of l into frame k
            float bk[12];
            inv_affine(rk, bk);
            bool rawA = false;
#pragma unroll
            for (int c = 0; c < 8; ++c) {
                float cx = ((c >> 2) & 1) ? bmxl[0] : bmnl[0];
                float cy = ((c >> 1) & 1) ? bmxl[1] : bmnl[1];
                float cz = (c & 1) ? bmxl[2] : bmnl[2];
                float px = rl[0] * cx + rl[1] * cy + rl[2] * cz + rl[3];
                float py = rl[4] * cx + rl[5] * cy + rl[6] * cz + rl[7];
                float pz = rl[8] * cx + rl[9] * cy + rl[10] * cz + rl[11];
                float x = bk[0] * px + bk[1] * py + bk[2] * pz + bk[3];
                float y = bk[4] * px + bk[5] * py + bk[6] * pz + bk[7];
                float z = bk[8] * px + bk[9] * py + bk[10] * pz + bk[11];
                rawA = rawA || (x > bmnk[0] + EPSF && x < bmxk[0] - EPSF &&
                                y > bmnk[1] + EPSF && y < bmxk[1] - EPSF &&
                                z > bmnk[2] + EPSF && z < bmxk[2] - EPSF);
            }
            bit = rawA;
        }
        if (dB && !bit) {  // corners of k into frame l
            float bl[12];
            inv_affine(rl, bl);
            bool rawB = false;
#pragma unroll
            for (int c = 0; c < 8; ++c) {
                float cx = ((c >> 2) & 1) ? bmxk[0] : bmnk[0];
                float cy = ((c >> 1) & 1) ? bmxk[1] : bmnk[1];
                float cz = (c & 1) ? bmxk[2] : bmnk[2];
                float px = rk[0] * cx + rk[1] * cy + rk[2] * cz + rk[3];
                float py = rk[4] * cx + rk[5] * cy + rk[6] * cz + rk[7];
                float pz = rk[8] * cx + rk[9] * cy + rk[10] * cz + rk[11];
                float x = bl[0] * px + bl[1] * py + bl[2] * pz + bl[3];
                float y = bl[4] * px + bl[5] * py + bl[6] * pz + bl[7];
                float z = bl[8] * px + bl[9] * py + bl[10] * pz + bl[11];
                rawB = rawB || (x > bmnl[0] + EPSF && x < bmxl[0] - EPSF &&
                                y > bmnl[1] + EPSF && y < bmxl[1] - EPSF &&
                                z > bmnl[2] + EPSF && z < bmxl[2] - EPSF);
            }
            bit = rawB;
        }
    }
    uint64_t word = __ballot(bit ? 1 : 0);
    __shared__ uint32_t wcnt[4];
    if (lane == 0) {
        bm[(size_t)k * 16 + j * 4 + wave] = word;
        wcnt[wave] = (uint32_t)__popcll(word);
    }
    __syncthreads();
    if (t == 0) tileCnt[(size_t)k * 4 + j] = wcnt[0] + wcnt[1] + wcnt[2] + wcnt[3];
}

// 128 blocks x 512 threads: block b owns rows 8b..8b+7 (one per wave) + a slice
// of the complement -1 fill. Blocks 128..129: hposed output (independent).
__global__ void k_compact(const float* __restrict__ bbmin, const float* __restrict__ bbmax,
                          const float* __restrict__ A,
                          const uint64_t* __restrict__ bm,
                          const uint32_t* __restrict__ tileCnt,
                          float* __restrict__ out_hposed, float* __restrict__ out) {
    int b = blockIdx.x;
    int t = threadIdx.x;  // 512 threads
    if (b >= 128) {  // pose blocks: write hposed (output 0)
        int k = (b - 128) * 512 + t;
        float r[12];
#pragma unroll
        for (int i = 0; i < 3; ++i) {
            float4 a4 = *(const float4*)(A + (size_t)k * 16 + i * 4);
            r[i * 4 + 0] = a4.x; r[i * 4 + 1] = a4.y; r[i * 4 + 2] = a4.z; r[i * 4 + 3] = a4.w;
        }
        float bmn[3], bmx[3];
#pragma unroll
        for (int i = 0; i < 3; ++i) { bmn[i] = bbmin[k * 3 + i]; bmx[i] = bbmax[k * 3 + i]; }
#pragma unroll
        for (int c = 0; c < 8; ++c) {
            float cx = ((c >> 2) & 1) ? bmx[0] : bmn[0];
            float cy = ((c >> 1) & 1) ? bmx[1] : bmn[1];
            float cz = (c & 1) ? bmx[2] : bmn[2];
#pragma unroll
            for (int i = 0; i < 3; ++i)
                out_hposed[(size_t)k * 24 + c * 3 + i] =
                    r[i * 4 + 0] * cx + r[i * 4 + 1] * cy + r[i * 4 + 2] * cz + r[i * 4 + 3];
        }
        return;
    }

    int wave = t >> 6, lane = t & 63;
    int k0 = 8 * b;
    __shared__ uint32_t baseW[8], totW[8], rowc[8];

    // per-thread: 2 strided rows; mask tile components by validity (j*256<=row)
    uint32_t sm = 0, st = 0;
#pragma unroll
    for (int rr = 0; rr < 2; ++rr) {
        int row = t + rr * 512;
        uint4 c4 = *(const uint4*)(tileCnt + (size_t)row * 4);
        uint32_t v = c4.x + ((row >= 256) ? c4.y : 0u) + ((row >= 512) ? c4.z : 0u) +
                     ((row >= 768) ? c4.w : 0u);
        sm += (row < k0) ? v : 0u;
        st += v;
    }
#pragma unroll
    for (int off = 32; off > 0; off >>= 1) { sm += __shfl_xor(sm, off); st += __shfl_xor(st, off); }
    if (lane == 0) { baseW[wave] = sm; totW[wave] = st; }
    if (t < 8) {  // in-block row counts
        int row = k0 + t;
        uint4 c4 = *(const uint4*)(tileCnt + (size_t)row * 4);
        rowc[t] = c4.x + ((row >= 256) ? c4.y : 0u) + ((row >= 512) ? c4.z : 0u) +
                  ((row >= 768) ? c4.w : 0u);
    }
    __syncthreads();
    uint32_t base = 0, total = 0;
#pragma unroll
    for (int wv = 0; wv < 8; ++wv) { base += baseW[wv]; total += totW[wv]; }

    // complement fill: positions [total, K*K) in float2 units get (-1,-1);
    // pair writes below cover [0, total) exactly -> disjoint, race-free.
    float2* o2 = (float2*)out;
    for (uint32_t i = total + (uint32_t)b * 512 + t; i < (uint32_t)(KBOX * KBOX); i += 128 * 512)
        o2[i] = make_float2(-1.f, -1.f);

    // wave w compacts row k0+w
    uint32_t startw = base;
#pragma unroll
    for (int r = 0; r < 8; ++r)
        if (r < wave) startw += rowc[r];
    int k = k0 + wave;
    uint64_t w = (lane < 16 && lane * 64 <= k) ? bm[(size_t)k * 16 + lane] : 0ull;
    int c = (int)__popcll(w);
    int p = c;
#pragma unroll
    for (int off = 1; off < 64; off <<= 1) {
        int u = __shfl_up(p, off);
        if (lane >= off) p += u;
    }
    int ofs = (int)startw + (p - c);
    float fk = (float)k;
    while (w) {
        int bpos = __builtin_ctzll(w);
        int col = lane * 64 + bpos;
        out[2 * (size_t)ofs + 0] = (float)col;  // min = col (tril => col <= row)
        out[2 * (size_t)ofs + 1] = fk;          // max = row
        ++ofs;
        w &= w - 1;
    }
}

extern "C" void kernel_launch(void* const* d_in, const int* in_sizes, int n_in,
                              void* d_out, int out_size, void* d_ws, size_t ws_size,
                              hipStream_t stream) {
    const float* bbmin = (const float*)d_in[0];
    const float* bbmax = (const float*)d_in[1];
    const float* A = (const float*)d_in[2];
    const uint8_t* dis = (const uint8_t*)d_in[3];
    float* out = (float*)d_out;

    char* ws = (char*)d_ws;
    uint64_t* bm = (uint64_t*)(ws + BM_OFF);
    uint32_t* tileCnt = (uint32_t*)(ws + TC_OFF);

    k_main<<<ACT_TILES, 256, 0, stream>>>(bbmin, bbmax, A, dis, bm, tileCnt);
    k_compact<<<130, 512, 0, stream>>>(bbmin, bbmax, A, bm, tileCnt, out, out + KBOX * 24);
}